// Round 6
// baseline (148.034 us; speedup 1.0000x reference)
//
#include <hip/hip_runtime.h>
#include <hip/hip_fp16.h>

#define CIN   32
#define COUT  64
#define TT    8
#define HH    56
#define WW    56
#define KK    27
#define SP    (TT * HH * WW)   // 25088
#define NB    2
#define NBLK  784              // prep: (NB*SP)/64
#define DBLK  1568             // dconv: (NB*SP)/32 -- 32 positions per block
#define KSPLIT 14              // half 0: taps [0,14)+bias; half 1: [14,27)

typedef __attribute__((ext_vector_type(8))) _Float16 half8;
typedef __attribute__((ext_vector_type(4))) float    f32x4;

// d_ws layout
#define WF_OFF   0                    // weight A-frags (16x16x32): 110,592 B
#define XTH_OFF  (128 << 10)          // xTh fp16 channel-last: 3,211,264 B

// prep: blocks [0,784): x [N][C][SP] fp32 -> xTh [N][SP][C] fp16
//       blocks [784,811): weight -> 16x16x32 A-fragments
//       wf[k][ct][lane][j] = w[co = ct*16 + (lane&15)][c = (lane>>4)*8 + j][k]
__global__ __launch_bounds__(256) void prep_kernel(const float* __restrict__ x,
                                                   const float* __restrict__ w,
                                                   __half* __restrict__ xTh,
                                                   __half* __restrict__ wf) {
    const int b = blockIdx.x;
    const int t = threadIdx.x;
    if (b < NBLK) {
        __shared__ float sm[CIN][65];
        const int s0 = b * 64, n = s0 / SP, sp0 = s0 % SP;
#pragma unroll
        for (int it = 0; it < 8; ++it) {
            const int idx = it * 256 + t, c = idx >> 6, l = idx & 63;
            sm[c][l] = x[((size_t)n * CIN + c) * SP + sp0 + l];
        }
        __syncthreads();
#pragma unroll
        for (int it = 0; it < 4; ++it) {
            const int idx = it * 256 + t, l = idx >> 4, cp = idx & 15;
            ((__half2*)xTh)[((size_t)n * SP + sp0 + l) * (CIN / 2) + cp] =
                __floats2half2_rn(sm[2 * cp][l], sm[2 * cp + 1][l]);
        }
    } else {
        const int k = b - NBLK;        // 2048 elements: [ct(4)][lane(64)][j(8)]
#pragma unroll
        for (int it = 0; it < 8; ++it) {
            const int idx  = it * 256 + t;
            const int j    = idx & 7;
            const int lane = (idx >> 3) & 63;
            const int ct   = (idx >> 9) & 3;
            const int co   = ct * 16 + (lane & 15);
            const int c    = (lane >> 4) * 8 + j;
            wf[(((size_t)k * 4 + ct) * 64 + lane) * 8 + j] =
                __float2half(w[((size_t)co * CIN + c) * KK + k]);
        }
    }
}

// 256-thread blocks: 4 waves = 2 position-tiles x 2 tap-halves.
// Changes vs R5 (both attack the per-tap serial chain, the proven bottleneck):
//  1. B-persona gathers: lane reads pos=lane&15, channels (lane>>4)*8..+7 --
//     vacc lands directly in the MFMA B-frag layout; the 4 ds_bpermute per
//     tap (and their DS latency + 677k conflict cycles) are eliminated.
//     Lanes {p,p+16,p+32,p+48} cover the same 64B xTh line as the old quads.
//  2. wf A-frags prefetched one tap ahead into named half8 regs: VMEM queue
//     per tap is [gathers(k) x8, wf(k+1) x4]; hfma drains gathers oldest-
//     first, MFMA reads wf from registers -> no per-tap vmcnt hard drain.
__global__ __launch_bounds__(256, 4) void dconv3d_kernel(const __half* __restrict__ xTh,
                                                         const float* __restrict__ off,
                                                         const __half* __restrict__ wf,
                                                         const float* __restrict__ bias,
                                                         float* __restrict__ out) {
    // 10.4 KB: offsets [81][32] during main loop; combine [16][2][64] at end
    __shared__ __align__(16) char smem[81 * 32 * 4];
    float (*offs)[32] = reinterpret_cast<float(*)[32]>(smem);
    float (*cmb)[2][64] = reinterpret_cast<float(*)[2][64]>(smem);

    const int t    = threadIdx.x;
    const int lane = t & 63;
    const int wv   = t >> 6;           // 0..3
    const int wpos = wv & 1;           // position-tile (16 positions each)
    const int half = wv >> 1;          // 0: taps [0,14)+bias, 1: taps [14,27)

    // unified persona (gather == MFMA B/C layout)
    const int posI = lane & 15;        // position within tile
    const int jg   = lane >> 4;        // channel-block (B) / C row-group

    // XCD-aware swizzle (bijective on 1568; 784*32 == SP so no batch crossing)
    const int sb  = (blockIdx.x & 7) * 196 + (blockIdx.x >> 3);
    const int s0  = sb * 32;
    const int n   = s0 / SP;
    const int spb = s0 % SP;

    // ---- stage offsets: off[n][row][spb..spb+32) -> offs[row][0..32), row=k*3+d
    {
        const float* offbase = off + ((size_t)n * (3 * KK)) * SP + spb;
        // 81 rows x 8 float4 = 648 float4 elements
        for (int i = t; i < 81 * 8; i += 256) {
            const int row = i >> 3, q = i & 7;
            *(float4*)&offs[row][q * 4] = *(const float4*)(offbase + (size_t)row * SP + q * 4);
        }
    }
    __syncthreads();

    const int sp = spb + wpos * 16 + posI;
    const int to = sp / (HH * WW);
    const int hw = sp % (HH * WW);
    const int ho = hw / WW;
    const int wo = hw % WW;
    const int pl = wpos * 16 + posI;   // local position index 0..31

    // bias rides in the MFMA C operand (half 0 only)
    f32x4 acc[4];
#pragma unroll
    for (int ct = 0; ct < 4; ++ct)
#pragma unroll
        for (int r = 0; r < 4; ++r)
            acc[ct][r] = half ? 0.f : bias[ct * 16 + jg * 4 + r];

    const __half* xn = xTh + (size_t)n * SP * CIN;

    const int k0 = half ? KSPLIT : 0;
    const int k1 = half ? KK : KSPLIT;

    // wf A-frag double set for one-tap-ahead prefetch (named regs: proven
    // non-spilling in R2/R3 even under pressure)
    half8 wc0, wc1, wc2, wc3, wn0, wn1, wn2, wn3;
    {
        const __half* wp = wf + ((size_t)k0 * 256 + lane) * 8;
        wc0 = *(const half8*)(wp);
        wc1 = *(const half8*)(wp + 512);
        wc2 = *(const half8*)(wp + 1024);
        wc3 = *(const half8*)(wp + 1536);
    }

#pragma unroll 2
    for (int k = k0; k < k1; ++k) {
        const int kt  = k / 9;
        const int khh = (k / 3) % 3;
        const int kww = k % 3;

        const float pt_ = (float)(to - 1 + kt)  + offs[k * 3 + 0][pl];
        const float ph_ = (float)(ho - 1 + khh) + offs[k * 3 + 1][pl];
        const float pw_ = (float)(wo - 1 + kww) + offs[k * 3 + 2][pl];

        const float ft = floorf(pt_), fh = floorf(ph_), fw = floorf(pw_);
        const float lt = pt_ - ft, lh = ph_ - fh, lw = pw_ - fw;
        const int t0 = (int)ft, h0 = (int)fh, w0 = (int)fw;
        const int t1 = t0 + 1, h1 = h0 + 1, w1 = w0 + 1;

        // unsigned-range trick: (unsigned)v < LIM  <=>  0 <= v < LIM
        float awt[2], awh[2], aww[2];
        int   it2[2], ih2[2], iw2[2];
        awt[0] = ((unsigned)t0 < TT) ? (1.f - lt) : 0.f;
        awt[1] = ((unsigned)t1 < TT) ? lt : 0.f;
        it2[0] = min(max(t0, 0), TT - 1);  it2[1] = min(max(t1, 0), TT - 1);
        awh[0] = ((unsigned)h0 < HH) ? (1.f - lh) : 0.f;
        awh[1] = ((unsigned)h1 < HH) ? lh : 0.f;
        ih2[0] = min(max(h0, 0), HH - 1);  ih2[1] = min(max(h1, 0), HH - 1);
        aww[0] = ((unsigned)w0 < WW) ? (1.f - lw) : 0.f;
        aww[1] = ((unsigned)w1 < WW) ? lw : 0.f;
        iw2[0] = min(max(w0, 0), WW - 1);  iw2[1] = min(max(w1, 0), WW - 1);

        // base + delta address decomposition (exact: clamped deltas are
        // per-axis constants across the 8 corners)
        const int dT   = (it2[1] - it2[0]) * (HH * WW);
        const int dH   = (ih2[1] - ih2[0]) * WW;
        const int dW   = iw2[1] - iw2[0];
        const int base = (it2[0] * HH + ih2[0]) * WW + iw2[0];

        int   a[8];
        float cw[8];
        a[0] = base;           a[1] = base + dW;
        a[2] = base + dH;      a[3] = a[2] + dW;
        a[4] = base + dT;      a[5] = a[4] + dW;
        a[6] = a[4] + dH;      a[7] = a[6] + dW;
#pragma unroll
        for (int ci = 0; ci < 8; ++ci) {
            const int i0 = ci >> 2, i1 = (ci >> 1) & 1, i2 = ci & 1;
            cw[ci] = awt[i0] * awh[i1] * aww[i2];
        }

        // gathers in B-persona: lane reads 16B chunk jg of the 64B line of
        // its position's corner voxel
        float4 g[8];
#pragma unroll
        for (int ci = 0; ci < 8; ++ci)
            g[ci] = *(const float4*)(xn + (size_t)a[ci] * CIN + jg * 8);

        // prefetch wf(k+1) AFTER the gathers (newest in queue -> stays in
        // flight across this tap's hfma/MFMA; consumed from regs next tap)
        {
            const int kn = (k + 1 < k1) ? k + 1 : k;
            const __half* wpn = wf + ((size_t)kn * 256 + lane) * 8;
            wn0 = *(const half8*)(wpn);
            wn1 = *(const half8*)(wpn + 512);
            wn2 = *(const half8*)(wpn + 1024);
            wn3 = *(const half8*)(wpn + 1536);
        }

        // weighted corner reduction -- result is directly the B-fragment
        union { __half2 h2[4]; half8 h8; } u;
        u.h2[0] = __floats2half2_rn(0.f, 0.f);
        u.h2[1] = u.h2[0]; u.h2[2] = u.h2[0]; u.h2[3] = u.h2[0];
#pragma unroll
        for (int ci = 0; ci < 8; ++ci) {
            const __half2* uh = (const __half2*)&g[ci];
            const __half2 cw2 = __float2half2_rn(cw[ci]);
            u.h2[0] = __hfma2(cw2, uh[0], u.h2[0]);
            u.h2[1] = __hfma2(cw2, uh[1], u.h2[1]);
            u.h2[2] = __hfma2(cw2, uh[2], u.h2[2]);
            u.h2[3] = __hfma2(cw2, uh[3], u.h2[3]);
        }
        const half8 bfrag = u.h8;

        acc[0] = __builtin_amdgcn_mfma_f32_16x16x32_f16(wc0, bfrag, acc[0], 0, 0, 0);
        acc[1] = __builtin_amdgcn_mfma_f32_16x16x32_f16(wc1, bfrag, acc[1], 0, 0, 0);
        acc[2] = __builtin_amdgcn_mfma_f32_16x16x32_f16(wc2, bfrag, acc[2], 0, 0, 0);
        acc[3] = __builtin_amdgcn_mfma_f32_16x16x32_f16(wc3, bfrag, acc[3], 0, 0, 0);

        wc0 = wn0; wc1 = wn1; wc2 = wn2; wc3 = wn3;
    }

    // LDS reuse boundary: all offset reads must be done before combine writes
    __syncthreads();
    if (half == 1) {
#pragma unroll
        for (int ct = 0; ct < 4; ++ct)
#pragma unroll
            for (int r = 0; r < 4; ++r) cmb[ct * 4 + r][wpos][lane] = acc[ct][r];
    }
    __syncthreads();
    if (half == 0) {
        // C/D map (16x16): col=lane&15 (pos), row=(lane>>4)*4+reg (co)
#pragma unroll
        for (int ct = 0; ct < 4; ++ct)
#pragma unroll
            for (int r = 0; r < 4; ++r) {
                const int co = ct * 16 + jg * 4 + r;
                out[((size_t)n * COUT + co) * SP + spb + wpos * 16 + posI] =
                    acc[ct][r] + cmb[ct * 4 + r][wpos][lane];
            }
    }
}

extern "C" void kernel_launch(void* const* d_in, const int* in_sizes, int n_in,
                              void* d_out, int out_size, void* d_ws, size_t ws_size,
                              hipStream_t stream) {
    const float* x    = (const float*)d_in[0];
    const float* off  = (const float*)d_in[1];
    const float* w    = (const float*)d_in[2];
    const float* bias = (const float*)d_in[3];
    float* out        = (float*)d_out;

    __half* wf  = (__half*)((char*)d_ws + WF_OFF);
    __half* xTh = (__half*)((char*)d_ws + XTH_OFF);

    prep_kernel<<<NBLK + KK, 256, 0, stream>>>(x, w, xTh, wf);
    dconv3d_kernel<<<DBLK, 256, 0, stream>>>(xTh, off, wf, bias, out);
}

// Round 7
// 120.391 us; speedup vs baseline: 1.2296x; 1.2296x over previous
//
#include <hip/hip_runtime.h>
#include <hip/hip_fp16.h>

#define CIN   32
#define COUT  64
#define TT    8
#define HH    56
#define WW    56
#define KK    27
#define SP    (TT * HH * WW)   // 25088
#define NB    2
#define NBLK  784              // prep: (NB*SP)/64
#define DBLK  1568             // dconv: (NB*SP)/32 -- 32 positions per block
#define KSPLIT 14              // half 0: taps [0,14)+bias; half 1: [14,27)

typedef __attribute__((ext_vector_type(8))) _Float16 half8;
typedef __attribute__((ext_vector_type(4))) float    f32x4;

// d_ws layout
#define WF_OFF   0                    // weight A-frags (16x16x32): 110,592 B
#define XTH_OFF  (128 << 10)          // xTh fp16 channel-last: 3,211,264 B

// prep: blocks [0,784): x [N][C][SP] fp32 -> xTh [N][SP][C] fp16
//       blocks [784,811): weight -> 16x16x32 A-fragments
//       wf[k][ct][lane][j] = w[co = ct*16 + (lane&15)][c = (lane>>4)*8 + j][k]
__global__ __launch_bounds__(256) void prep_kernel(const float* __restrict__ x,
                                                   const float* __restrict__ w,
                                                   __half* __restrict__ xTh,
                                                   __half* __restrict__ wf) {
    const int b = blockIdx.x;
    const int t = threadIdx.x;
    if (b < NBLK) {
        __shared__ float sm[CIN][65];
        const int s0 = b * 64, n = s0 / SP, sp0 = s0 % SP;
#pragma unroll
        for (int it = 0; it < 8; ++it) {
            const int idx = it * 256 + t, c = idx >> 6, l = idx & 63;
            sm[c][l] = x[((size_t)n * CIN + c) * SP + sp0 + l];
        }
        __syncthreads();
#pragma unroll
        for (int it = 0; it < 4; ++it) {
            const int idx = it * 256 + t, l = idx >> 4, cp = idx & 15;
            ((__half2*)xTh)[((size_t)n * SP + sp0 + l) * (CIN / 2) + cp] =
                __floats2half2_rn(sm[2 * cp][l], sm[2 * cp + 1][l]);
        }
    } else {
        const int k = b - NBLK;        // 2048 elements: [ct(4)][lane(64)][j(8)]
#pragma unroll
        for (int it = 0; it < 8; ++it) {
            const int idx  = it * 256 + t;
            const int j    = idx & 7;
            const int lane = (idx >> 3) & 63;
            const int ct   = (idx >> 9) & 3;
            const int co   = ct * 16 + (lane & 15);
            const int c    = (lane >> 4) * 8 + j;
            wf[(((size_t)k * 4 + ct) * 64 + lane) * 8 + j] =
                __float2half(w[((size_t)co * CIN + c) * KK + k]);
        }
    }
}

// 256-thread blocks: 4 waves = 2 position-tiles x 2 tap-halves.
// R5 structure (quad-persona gathers + bpermute repack: 16 distinct 64B
// lines per gather instr, 100% line utilization) with the tap loops FULLY
// UNROLLED over literal bounds. R6 proved cross-tap ILP is the dominant
// mechanism (losing unroll-2 cost +40%); full unroll hands the scheduler
// the entire 13/14-tap dataflow graph (k compile-time: kt/khh/kww consts,
// offs[] reads become ds_read offset: immediates). launch_bounds(256,4)
// raises the VGPR cap to 128 so the scheduler can hold multiple taps'
// gathers in flight -- R5 showed extra waves are worthless (occ 41->53%,
// time flat), so trading wave slots for registers is free.
__global__ __launch_bounds__(256, 4) void dconv3d_kernel(const __half* __restrict__ xTh,
                                                         const float* __restrict__ off,
                                                         const __half* __restrict__ wf,
                                                         const float* __restrict__ bias,
                                                         float* __restrict__ out) {
    // 10.4 KB: offsets [81][32] during main loop; combine [16][2][64] at end
    __shared__ __align__(16) char smem[81 * 32 * 4];
    float (*offs)[32] = reinterpret_cast<float(*)[32]>(smem);
    float (*cmb)[2][64] = reinterpret_cast<float(*)[2][64]>(smem);

    const int t    = threadIdx.x;
    const int lane = t & 63;
    const int wv   = t >> 6;           // 0..3
    const int wpos = wv & 1;           // position-tile (16 positions each)
    const int half = wv >> 1;          // 0: taps [0,14)+bias, 1: taps [14,27)

    // interp persona (quad-aligned gathers)
    const int posI = lane >> 2;        // 0..15
    const int cgI  = lane & 3;         // channels cgI*8 .. +7
    // gemm persona (MFMA B/C fixed layout)
    const int jg   = lane >> 4;        // B k-group / C row-group

    // bpermute source lane: src = 4*(lane&15) + (lane>>4); byte addr = src*4
    const int bp_addr = (((lane & 15) << 2) | jg) << 2;

    // XCD-aware swizzle (bijective on 1568; 784*32 == SP so no batch crossing)
    const int sb  = (blockIdx.x & 7) * 196 + (blockIdx.x >> 3);
    const int s0  = sb * 32;
    const int n   = s0 / SP;
    const int spb = s0 % SP;

    // ---- stage offsets: off[n][row][spb..spb+32) -> offs[row][0..32), row=k*3+d
    {
        const float* offbase = off + ((size_t)n * (3 * KK)) * SP + spb;
        // 81 rows x 8 float4 = 648 float4 elements
        for (int i = t; i < 81 * 8; i += 256) {
            const int row = i >> 3, q = i & 7;
            *(float4*)&offs[row][q * 4] = *(const float4*)(offbase + (size_t)row * SP + q * 4);
        }
    }
    __syncthreads();

    const int sp = spb + wpos * 16 + posI;
    const int to = sp / (HH * WW);
    const int hw = sp % (HH * WW);
    const int ho = hw / WW;
    const int wo = hw % WW;
    const int pl = wpos * 16 + posI;   // local position index 0..31

    // bias rides in the MFMA C operand (half 0 only)
    f32x4 acc[4];
#pragma unroll
    for (int ct = 0; ct < 4; ++ct)
#pragma unroll
        for (int r = 0; r < 4; ++r)
            acc[ct][r] = half ? 0.f : bias[ct * 16 + jg * 4 + r];

    const __half* xn = xTh + (size_t)n * SP * CIN;

    auto tap = [&](int k) {
        const int kt  = k / 9;
        const int khh = (k / 3) % 3;
        const int kww = k % 3;

        const float pt_ = (float)(to - 1 + kt)  + offs[k * 3 + 0][pl];
        const float ph_ = (float)(ho - 1 + khh) + offs[k * 3 + 1][pl];
        const float pw_ = (float)(wo - 1 + kww) + offs[k * 3 + 2][pl];

        const float ft = floorf(pt_), fh = floorf(ph_), fw = floorf(pw_);
        const float lt = pt_ - ft, lh = ph_ - fh, lw = pw_ - fw;
        const int t0 = (int)ft, h0 = (int)fh, w0 = (int)fw;
        const int t1 = t0 + 1, h1 = h0 + 1, w1 = w0 + 1;

        // unsigned-range trick: (unsigned)v < LIM  <=>  0 <= v < LIM
        float awt[2], awh[2], aww[2];
        int   it2[2], ih2[2], iw2[2];
        awt[0] = ((unsigned)t0 < TT) ? (1.f - lt) : 0.f;
        awt[1] = ((unsigned)t1 < TT) ? lt : 0.f;
        it2[0] = min(max(t0, 0), TT - 1);  it2[1] = min(max(t1, 0), TT - 1);
        awh[0] = ((unsigned)h0 < HH) ? (1.f - lh) : 0.f;
        awh[1] = ((unsigned)h1 < HH) ? lh : 0.f;
        ih2[0] = min(max(h0, 0), HH - 1);  ih2[1] = min(max(h1, 0), HH - 1);
        aww[0] = ((unsigned)w0 < WW) ? (1.f - lw) : 0.f;
        aww[1] = ((unsigned)w1 < WW) ? lw : 0.f;
        iw2[0] = min(max(w0, 0), WW - 1);  iw2[1] = min(max(w1, 0), WW - 1);

        // base + delta address decomposition (exact: clamped deltas are
        // per-axis constants across the 8 corners)
        const int dT   = (it2[1] - it2[0]) * (HH * WW);
        const int dH   = (ih2[1] - ih2[0]) * WW;
        const int dW   = iw2[1] - iw2[0];
        const int base = (it2[0] * HH + ih2[0]) * WW + iw2[0];

        int   a[8];
        float cw[8];
        a[0] = base;           a[1] = base + dW;
        a[2] = base + dH;      a[3] = a[2] + dW;
        a[4] = base + dT;      a[5] = a[4] + dW;
        a[6] = a[4] + dH;      a[7] = a[6] + dW;
#pragma unroll
        for (int ci = 0; ci < 8; ++ci) {
            const int i0 = ci >> 2, i1 = (ci >> 1) & 1, i2 = ci & 1;
            cw[ci] = awt[i0] * awh[i1] * aww[i2];
        }

        // gathers: quad-aligned, one 64 B xTh line per corner per quad
        float4 g[8];
#pragma unroll
        for (int ci = 0; ci < 8; ++ci)
            g[ci] = *(const float4*)(xn + (size_t)a[ci] * CIN + cgI * 8);

        __half2 vacc[4];
#pragma unroll
        for (int j = 0; j < 4; ++j) vacc[j] = __floats2half2_rn(0.f, 0.f);
#pragma unroll
        for (int ci = 0; ci < 8; ++ci) {
            const __half2* uh = (const __half2*)&g[ci];
            const __half2 cw2 = __float2half2_rn(cw[ci]);
            vacc[0] = __hfma2(cw2, uh[0], vacc[0]);
            vacc[1] = __hfma2(cw2, uh[1], vacc[1]);
            vacc[2] = __hfma2(cw2, uh[2], vacc[2]);
            vacc[3] = __hfma2(cw2, uh[3], vacc[3]);
        }

        // repack (pos=lane>>2, ch=lane&3) -> B-frag (pos=lane&15, ch-grp=lane>>4)
        union { __half2 h2[4]; int i[4]; half8 h8; } u, v;
#pragma unroll
        for (int d = 0; d < 4; ++d) u.h2[d] = vacc[d];
#pragma unroll
        for (int d = 0; d < 4; ++d)
            v.i[d] = __builtin_amdgcn_ds_bpermute(bp_addr, u.i[d]);
        const half8 bfrag = v.h8;

#pragma unroll
        for (int ct = 0; ct < 4; ++ct) {
            const half8 af = *(const half8*)(wf + (((size_t)k * 4 + ct) * 64 + lane) * 8);
            acc[ct] = __builtin_amdgcn_mfma_f32_16x16x32_f16(af, bfrag, acc[ct], 0, 0, 0);
        }
    };

    if (half == 0) {
#pragma unroll
        for (int k = 0; k < KSPLIT; ++k) tap(k);
    } else {
#pragma unroll
        for (int k = KSPLIT; k < KK; ++k) tap(k);
    }

    // LDS reuse boundary: all offset reads must be done before combine writes
    __syncthreads();
    if (half == 1) {
#pragma unroll
        for (int ct = 0; ct < 4; ++ct)
#pragma unroll
            for (int r = 0; r < 4; ++r) cmb[ct * 4 + r][wpos][lane] = acc[ct][r];
    }
    __syncthreads();
    if (half == 0) {
        // C/D map (16x16): col=lane&15 (pos), row=(lane>>4)*4+reg (co)
#pragma unroll
        for (int ct = 0; ct < 4; ++ct)
#pragma unroll
            for (int r = 0; r < 4; ++r) {
                const int co = ct * 16 + jg * 4 + r;
                out[((size_t)n * COUT + co) * SP + spb + wpos * 16 + (lane & 15)] =
                    acc[ct][r] + cmb[ct * 4 + r][wpos][lane];
            }
    }
}

extern "C" void kernel_launch(void* const* d_in, const int* in_sizes, int n_in,
                              void* d_out, int out_size, void* d_ws, size_t ws_size,
                              hipStream_t stream) {
    const float* x    = (const float*)d_in[0];
    const float* off  = (const float*)d_in[1];
    const float* w    = (const float*)d_in[2];
    const float* bias = (const float*)d_in[3];
    float* out        = (float*)d_out;

    __half* wf  = (__half*)((char*)d_ws + WF_OFF);
    __half* xTh = (__half*)((char*)d_ws + XTH_OFF);

    prep_kernel<<<NBLK + KK, 256, 0, stream>>>(x, w, xTh, wf);
    dconv3d_kernel<<<DBLK, 256, 0, stream>>>(xTh, off, wf, bias, out);
}